// Round 1
// 1169.045 us; speedup vs baseline: 1.0757x; 1.0757x over previous
//
#include <hip/hip_runtime.h>

typedef unsigned int uint;
typedef unsigned short ushort;

typedef short bfrag __attribute__((ext_vector_type(8)));   // 8 x bf16 (4 VGPRs)
typedef float f32x4 __attribute__((ext_vector_type(4)));

__device__ __forceinline__ ushort f2bf(float f) {
  uint u = __float_as_uint(f);
  u = (u + 0x7FFFu + ((u >> 16) & 1u)) >> 16;   // RNE
  return (ushort)u;
}
__device__ __forceinline__ float bf2f(ushort h) {
  return __uint_as_float(((uint)h) << 16);
}
// packed fp32x2 -> bf16x2, RNE (bit-identical to f2bf pairs), 1 instruction
__device__ __forceinline__ uint cvt_pk_bf16(float lo, float hi) {
  uint r;
  asm("v_cvt_pk_bf16_f32 %0, %1, %2" : "=v"(r) : "v"(lo), "v"(hi));
  return r;
}
__device__ __forceinline__ float sigmoidf(float t) {
  return __builtin_amdgcn_rcpf(1.0f + __expf(-t));
}

// ---------------------------------------------------------------------------
// Prep: pack Wq|Wk|Wv (fp32 [H][256][64]) into bf16 MFMA fragment order:
//   wb[gnt][kk][lane][j] = W[k = kk*32 + (lane>>4)*8 + j][n = gnt*16 + (lane&15)]
// (A- and B-fragment lane maps are identical, so this pack serves as the A
//  operand of mfma(W, x) — lane&15 = n becomes the output ROW.)
// Also W1T[j][c] = W1[c][j].
// ---------------------------------------------------------------------------
__global__ void prep_kernel(const float* __restrict__ Wq, const float* __restrict__ Wk,
                            const float* __restrict__ Wv, const float* __restrict__ W1,
                            ushort* __restrict__ wb, float* __restrict__ w1t) {
  int idx = blockIdx.x * 256 + threadIdx.x;
  if (idx < 196608) {
    int j    = idx & 7;
    int lane = (idx >> 3) & 63;
    int kk   = (idx >> 9) & 7;
    int gnt  = idx >> 12;                 // 0..47
    int head = gnt / 12;
    int nh   = (gnt % 12) * 16 + (lane & 15);   // 0..191 within head
    int k    = kk * 32 + (lane >> 4) * 8 + j;   // 0..255
    int sel  = nh >> 6, d = nh & 63;
    const float* W = (sel == 0) ? Wq : ((sel == 1) ? Wk : Wv);
    wb[idx] = f2bf(W[(head * 256 + k) * 64 + d]);
  }
  if (idx < 4096) {
    int j = idx >> 8, c = idx & 255;
    w1t[idx] = W1[c * 16 + j];
  }
}

// ---------------------------------------------------------------------------
// Fused: per block 16 samples (80 x-rows).
//  - stage x fp32->bf16 into swizzled LDS (one barrier, K=256 resident)
//  - per head: mfma(W,x) -> D[n][xrow]: lane holds 4 CONSECUTIVE qkv cols of
//    one row -> packed ds_write_b64 (+bias, cvt_pk). qkv row stride = 200
//    ushorts (100 words = 4 mod 32) -> bank-conflict-free writes.
//  - attention via MFMA: 2 diagonal 16x16 tiles/wave (2 samples each, m-rows
//    at stride 8), S = mfma(K,Q); softmax over m = shfl_xor(16/32) quad
//    reduce; w_m = 0.2*sum_l alpha = shfl_xor(1/2/4) l-group reduce.
//  - phase D: s += w.V (scalar, cheap), SE gate with r in regs + shfl.
// Barriers: 1 (stage) + 2/head (qkv cross-wave hazards) = 9. All wgt/sbuf
// dataflow is wave-local (sample's threads and attn lanes share wave s>>2);
// DS ops are in-order per wave, wave_barrier() fences compiler reordering.
// LDS: x 40960 + qkv 32000 + sbuf 8192 + wgt 512 = 81664 B -> 2 blocks/CU.
// ---------------------------------------------------------------------------
__global__ __launch_bounds__(256, 2)
void fused_kernel(const float* __restrict__ x,
                  const float* __restrict__ bq, const float* __restrict__ bk,
                  const float* __restrict__ bv,
                  const ushort* __restrict__ wb, const float* __restrict__ w1t,
                  const float* __restrict__ b1, const float* __restrict__ W2,
                  const float* __restrict__ b2, float* __restrict__ out) {
  __shared__ ushort xlds[20480];   // 80 rows x 256 bf16, 16B-chunk XOR swizzle
  __shared__ ushort qkv[16000];    // 80 rows x 200 bf16 (192 used), 400B row
  __shared__ ushort sbuf[4096];    // s: 16 samples x 256 bf16
  __shared__ float  wgt[128];      // [16][8]: w[sample][m], m=0..4

  const int tid  = threadIdx.x;
  const int lane = tid & 63;
  const int wave = tid >> 6;
  const int ln   = lane & 15;
  const int quad = lane >> 4;
  const int blk  = blockIdx.x;

  // ---- stage x tile: 20480 floats, fully coalesced float4, cvt to bf16
  {
    const float* xb = x + (size_t)blk * 20480;
#pragma unroll
    for (int it = 0; it < 20; ++it) {
      int f = it * 1024 + tid * 4;
      float4 v = *(const float4*)(xb + f);
      int row = f >> 8;
      int col = f & 255;
      int ch = col >> 3;
      int half = (col >> 2) & 1;
      int phys = ch ^ (row & 7);
      uint2 p;
      p.x = cvt_pk_bf16(v.x, v.y);
      p.y = cvt_pk_bf16(v.z, v.w);
      *(uint2*)(&xlds[row * 256 + phys * 8 + half * 4]) = p;
    }
  }
  __syncthreads();

  const int sample = tid >> 4;   // 0..15
  const int u      = tid & 15;   // 0..15

  // ---- attention lane mapping (head-independent, hoisted)
  const int sl   = ln >> 3;            // which sample within tile (0/1)
  const int mm   = ln & 7;             // m (as S-col: l) index, pad >=5
  const int qsel = quad - (sl << 1);   // 0: acc rows m=0..3; 1: row m=4
  const bool lo  = (qsel == 0), hi = (qsel == 1);
  const bool lv  = (mm < 5);
  int r0 = (wave * 4 + sl) * 5 + mm;      if (r0 > 79) r0 = 79;  // tile0 rows
  int r1 = (wave * 4 + 2 + sl) * 5 + mm;  if (r1 > 79) r1 = 79;  // tile1 rows
  const int bQ0 = r0 * 400 + quad * 16;   // byte base, Q cols
  const int bQ1 = r1 * 400 + quad * 16;

  for (int head = 0; head < 4; ++head) {
    f32x4 acc[5][3];   // [mt = xrow tile][nt = n tile]
#pragma unroll
    for (int mt = 0; mt < 5; ++mt)
#pragma unroll
      for (int nt = 0; nt < 3; ++nt)
        acc[mt][nt] = (f32x4){0.f, 0.f, 0.f, 0.f};

    // ---- K-loop: 8 steps of 32. x: ds_read_b128; W: global dwordx4 (L2)
#pragma unroll
    for (int kk = 0; kk < 8; ++kk) {
      bfrag a[5], b[3];
      int cb = kk * 4 + quad;
#pragma unroll
      for (int mt = 0; mt < 5; ++mt) {
        int row = mt * 16 + ln;
        int off = row * 256 + ((cb ^ (row & 7)) << 3);
        a[mt] = *(const bfrag*)(&xlds[off]);
      }
#pragma unroll
      for (int nt = 0; nt < 3; ++nt) {
        int goff = (((head * 12 + wave * 3 + nt) * 8 + kk) * 64 + lane) * 8;
        b[nt] = *(const bfrag*)(wb + goff);
      }
      // swapped operands: A = W (rows = n), B = x (cols = xrow)
#pragma unroll
      for (int nt = 0; nt < 3; ++nt)
#pragma unroll
        for (int mt = 0; mt < 5; ++mt)
          acc[mt][nt] = __builtin_amdgcn_mfma_f32_16x16x32_bf16(b[nt], a[mt], acc[mt][nt], 0, 0, 0);
    }

    // ---- C->LDS: D[n][xrow]: lane has 4 consecutive n-cols of row xrow
#pragma unroll
    for (int nt = 0; nt < 3; ++nt) {
      int nq = wave * 48 + nt * 16 + quad * 4;    // n base, 0..188
      int sel = nq >> 6, d0 = nq & 63;
      const float* bp = (sel == 0) ? bq : ((sel == 1) ? bk : bv);
      float4 bias = *(const float4*)(bp + head * 64 + d0);
#pragma unroll
      for (int mt = 0; mt < 5; ++mt) {
        int xr = mt * 16 + ln;
        uint2 p;
        p.x = cvt_pk_bf16(acc[mt][nt][0] + bias.x, acc[mt][nt][1] + bias.y);
        p.y = cvt_pk_bf16(acc[mt][nt][2] + bias.z, acc[mt][nt][3] + bias.w);
        *(uint2*)(&qkv[xr * 200 + nq]) = p;
      }
    }
    __syncthreads();

    // ---- attention S via MFMA: S[m,l] = mfma(K, Q), 2 tiles of 2 samples
    f32x4 s0 = {0.f, 0.f, 0.f, 0.f}, s1 = {0.f, 0.f, 0.f, 0.f};
    {
      const char* qb = (const char*)qkv;
#pragma unroll
      for (int kk = 0; kk < 2; ++kk) {
        bfrag qf0 = *(const bfrag*)(qb + bQ0 + kk * 64);          // Q cols 0..63
        bfrag kf0 = *(const bfrag*)(qb + bQ0 + 128 + kk * 64);    // K cols 64..127
        bfrag qf1 = *(const bfrag*)(qb + bQ1 + kk * 64);
        bfrag kf1 = *(const bfrag*)(qb + bQ1 + 128 + kk * 64);
        s0 = __builtin_amdgcn_mfma_f32_16x16x32_bf16(kf0, qf0, s0, 0, 0, 0);
        s1 = __builtin_amdgcn_mfma_f32_16x16x32_bf16(kf1, qf1, s1, 0, 0, 0);
      }
    }

    // ---- softmax over m (cross-quad) + w_m = 0.2*sum_l alpha (l-group)
    auto attn_tile = [&](const f32x4 sS, const int t) {
      float t0 = sS[0] * 0.0625f, t1 = sS[1] * 0.0625f;
      float t2 = sS[2] * 0.0625f, t3 = sS[3] * 0.0625f;
      float pm = lo ? fmaxf(fmaxf(t0, t1), fmaxf(t2, t3)) : (hi ? t0 : -1e30f);
      pm = fmaxf(pm, __shfl_xor(pm, 16));
      pm = fmaxf(pm, __shfl_xor(pm, 32));
      float e0 = __expf(t0 - pm), e1 = __expf(t1 - pm);
      float e2 = __expf(t2 - pm), e3 = __expf(t3 - pm);
      float ps = lo ? (e0 + e1 + e2 + e3) : (hi ? e0 : 0.f);
      ps += __shfl_xor(ps, 16);
      ps += __shfl_xor(ps, 32);
      float inv = 0.2f * __builtin_amdgcn_rcpf(ps);   // fold the 1/5 here
      float c0 = ((lo || hi) && lv) ? e0 * inv : 0.f;
      float c1 = (lo && lv) ? e1 * inv : 0.f;
      float c2 = (lo && lv) ? e2 * inv : 0.f;
      float c3 = (lo && lv) ? e3 * inv : 0.f;
      c0 += __shfl_xor(c0, 1); c0 += __shfl_xor(c0, 2); c0 += __shfl_xor(c0, 4);
      c1 += __shfl_xor(c1, 1); c1 += __shfl_xor(c1, 2); c1 += __shfl_xor(c1, 4);
      c2 += __shfl_xor(c2, 1); c2 += __shfl_xor(c2, 2); c2 += __shfl_xor(c2, 4);
      c3 += __shfl_xor(c3, 1); c3 += __shfl_xor(c3, 2); c3 += __shfl_xor(c3, 4);
      int smp = wave * 4 + t * 2 + sl;
      if (mm == 0) {
        if (qsel == 0) {
          *(float4*)(wgt + smp * 8) = make_float4(c0, c1, c2, c3);  // w[0..3]
        } else if (qsel == 1) {
          wgt[smp * 8 + 4] = c0;                                    // w[4]
        }
      }
    };
    attn_tile(s0, 0);
    attn_tile(s1, 1);
    __builtin_amdgcn_wave_barrier();   // wgt producer/consumer same wave; fence compiler

    // ---- phase D: s[head*64 + u*4 .. +3] = sum_m w[m] * V[m][.]
    {
      float4 w03 = *(const float4*)(wgt + sample * 8);
      float w4 = wgt[sample * 8 + 4];
      float a0 = 0.f, a1 = 0.f, a2 = 0.f, a3 = 0.f;
#pragma unroll
      for (int m = 0; m < 5; ++m) {
        float wv = (m == 0) ? w03.x : (m == 1) ? w03.y : (m == 2) ? w03.z
                 : (m == 3) ? w03.w : w4;
        uint2 v = *(const uint2*)(&qkv[(sample * 5 + m) * 200 + 128 + u * 4]);
        a0 += wv * bf2f((ushort)(v.x & 0xffff));
        a1 += wv * bf2f((ushort)(v.x >> 16));
        a2 += wv * bf2f((ushort)(v.y & 0xffff));
        a3 += wv * bf2f((ushort)(v.y >> 16));
      }
      uint2 p;
      p.x = cvt_pk_bf16(a0, a1);
      p.y = cvt_pk_bf16(a2, a3);
      *(uint2*)(&sbuf[sample * 256 + head * 64 + u * 4]) = p;
    }
    __syncthreads();   // protects qkv reuse by next head
  }

  // ---- SE gate: r[u] = relu(b1[u] + sum_c s[c]*W1T[u][c]) kept in register
  float rse;
  {
    float accv = b1[u];
    const float* wr = w1t + u * 256;
#pragma unroll 4
    for (int c = 0; c < 256; c += 4) {
      uint2 sv = *(const uint2*)(&sbuf[sample * 256 + c]);
      float4 wv = *(const float4*)(wr + c);
      accv += bf2f((ushort)(sv.x & 0xffff)) * wv.x + bf2f((ushort)(sv.x >> 16)) * wv.y
            + bf2f((ushort)(sv.y & 0xffff)) * wv.z + bf2f((ushort)(sv.y >> 16)) * wv.w;
    }
    rse = fmaxf(accv, 0.f);
  }

  // ---- g = sigmoid(r@W2 + b2); out = g * s   (thread u: cols u*16..u*16+15)
  {
    float g[16];
#pragma unroll
    for (int i = 0; i < 16; ++i) g[i] = b2[u * 16 + i];
    const int lbase = tid & 48;   // sample group base within wave
#pragma unroll
    for (int j = 0; j < 16; ++j) {
      float rj = __shfl(rse, lbase | j, 64);
      const float* w2r = W2 + j * 256 + u * 16;
#pragma unroll
      for (int i = 0; i < 16; i += 4) {
        float4 wv = *(const float4*)(w2r + i);
        g[i + 0] += rj * wv.x; g[i + 1] += rj * wv.y;
        g[i + 2] += rj * wv.z; g[i + 3] += rj * wv.w;
      }
    }
    float* ob = out + ((size_t)blk * 16 + sample) * 256 + u * 16;
#pragma unroll
    for (int i = 0; i < 16; i += 4) {
      int c = u * 16 + i;
      uint2 sv = *(const uint2*)(&sbuf[sample * 256 + c]);
      float4 ov;
      ov.x = sigmoidf(g[i + 0]) * bf2f((ushort)(sv.x & 0xffff));
      ov.y = sigmoidf(g[i + 1]) * bf2f((ushort)(sv.x >> 16));
      ov.z = sigmoidf(g[i + 2]) * bf2f((ushort)(sv.y & 0xffff));
      ov.w = sigmoidf(g[i + 3]) * bf2f((ushort)(sv.y >> 16));
      *(float4*)(ob + i) = ov;
    }
  }
}

extern "C" void kernel_launch(void* const* d_in, const int* in_sizes, int n_in,
                              void* d_out, int out_size, void* d_ws, size_t ws_size,
                              hipStream_t stream) {
  const float* x  = (const float*)d_in[0];
  const float* Wq = (const float*)d_in[1];
  const float* bq = (const float*)d_in[2];
  const float* Wk = (const float*)d_in[3];
  const float* bk = (const float*)d_in[4];
  const float* Wv = (const float*)d_in[5];
  const float* bv = (const float*)d_in[6];
  const float* W1 = (const float*)d_in[7];
  const float* b1 = (const float*)d_in[8];
  const float* W2 = (const float*)d_in[9];
  const float* b2 = (const float*)d_in[10];

  ushort* wb  = (ushort*)d_ws;                          // 393216 B
  float*  w1t = (float*)((char*)d_ws + 393216);         // 16384 B

  prep_kernel<<<768, 256, 0, stream>>>(Wq, Wk, Wv, W1, wb, w1t);
  fused_kernel<<<6250, 256, 0, stream>>>(x, bq, bk, bv, wb, w1t, b1, W2, b2,
                                         (float*)d_out);
}